// Round 5
// baseline (4019.704 us; speedup 1.0000x reference)
//
#include <hip/hip_runtime.h>
#include <stdint.h>

#define TT 256
#define BB 64
#define DD 1024
#define HH 1024
#define G3 3072

typedef unsigned long long ull;
typedef __attribute__((ext_vector_type(8))) short short8;
typedef __attribute__((ext_vector_type(4))) float f32x4;

__device__ __forceinline__ unsigned short f2bf(float f) {
  union { float f; unsigned int i; } v; v.f = f;
  unsigned int x = v.i;
  return (unsigned short)((x + 0x7fffu + ((x >> 16) & 1u)) >> 16);
}
__device__ __forceinline__ float bf2f(unsigned short u) {
  union { unsigned int i; float f; } v; v.i = ((unsigned int)u) << 16; return v.f;
}
__device__ __forceinline__ f32x4 mfma16(short8 a, short8 b, f32x4 c) {
  return __builtin_amdgcn_mfma_f32_16x16x32_bf16(a, b, c, 0, 0, 0);
}
__device__ __forceinline__ void gload_lds16(const void* g, void* l) {
  __builtin_amdgcn_global_load_lds((const __attribute__((address_space(1))) void*)g,
                                   (__attribute__((address_space(3))) void*)l,
                                   16, 0, 0);
}

// ---------------- f32 -> bf16 convert (vectorized) ----------------
__global__ void k_cvt_bf16(const float* __restrict__ in, unsigned short* __restrict__ out, int n4) {
  int i = blockIdx.x * blockDim.x + threadIdx.x;
  int stride = gridDim.x * blockDim.x;
  for (; i < n4; i += stride) {
    float4 v = ((const float4*)in)[i];
    ushort4 o;
    o.x = f2bf(v.x); o.y = f2bf(v.y); o.z = f2bf(v.z); o.w = f2bf(v.w);
    ((ushort4*)out)[i] = o;
  }
}

// ---------------- context projections + bias fold: E[64][3072] ----------------
__global__ __launch_bounds__(256) void k_ctx(
    const unsigned short* __restrict__ cjb, const unsigned short* __restrict__ heb,
    const unsigned short* __restrict__ Wchb, const unsigned short* __restrict__ Wzhb,
    const float* __restrict__ b_ih, const float* __restrict__ b_hh,
    const float* __restrict__ b_ch, const float* __restrict__ b_zh,
    float* __restrict__ E) {
  __shared__ f32x4 red[4][4][64];   // 16 KB
  int n0 = blockIdx.x * 16;         // 192 blocks
  int tid = threadIdx.x;
  int w = tid >> 6, l = tid & 63, lo = l & 15, hi = l >> 4;
  f32x4 acc[4];
#pragma unroll
  for (int r = 0; r < 4; r++) acc[r] = (f32x4){0.f, 0.f, 0.f, 0.f};
#pragma unroll 4
  for (int kk = 0; kk < 16; kk++) {
    int k = w * 512 + kk * 32;
    const unsigned short* Asrc = (k < 1024) ? cjb : heb;
    const unsigned short* Bsrc = (k < 1024) ? Wchb : Wzhb;
    int kw = (k < 1024) ? k : (k - 1024);
    int kof = kw + hi * 8;
    short8 bf = *(const short8*)(Bsrc + (size_t)(n0 + lo) * 1024 + kof);
#pragma unroll
    for (int r = 0; r < 4; r++) {
      short8 af = *(const short8*)(Asrc + (size_t)(r * 16 + lo) * 1024 + kof);
      acc[r] = mfma16(af, bf, acc[r]);
    }
  }
#pragma unroll
  for (int r = 0; r < 4; r++) red[w][r][l] = acc[r];
  __syncthreads();
  f32x4 s = red[0][w][l];
#pragma unroll
  for (int w2 = 1; w2 < 4; w2++) {
    f32x4 p = red[w2][w][l];
    s[0] += p[0]; s[1] += p[1]; s[2] += p[2]; s[3] += p[3];
  }
  int g = n0 + lo;
  float bias = b_ih[g] + b_ch[g] + b_zh[g] + ((g < 2048) ? b_hh[g] : 0.0f);
#pragma unroll
  for (int j = 0; j < 4; j++) {
    int b = w * 16 + hi * 4 + j;
    E[(size_t)b * G3 + g] = s[j] + bias;
  }
}

// ---------------- gi GEMM + E fold: giE[t*64+b][g] = X@Wih^T + E[b][g] (bf16) --------
__global__ __launch_bounds__(256) void k_gemm_gi(
    const unsigned short* __restrict__ Xb,   // [16384][1024] bf16
    const unsigned short* __restrict__ Wb,   // [3072][1024] bf16
    const float* __restrict__ E,             // [64][3072] f32
    unsigned short* __restrict__ gi) {       // [16384][3072] bf16
  __shared__ unsigned short As[128 * 32];
  __shared__ unsigned short Bs[128 * 32];
  int bid = blockIdx.x;
  int mt = bid & 127;
  int nt = bid >> 7;
  int m0 = mt * 128, n0 = nt * 128;
  int tid = threadIdx.x;
  int w = tid >> 6, l = tid & 63, lo = l & 15, hi = l >> 4;
  int wr = w >> 1, wc = w & 1;
  f32x4 acc[4][4];
#pragma unroll
  for (int i = 0; i < 4; i++)
#pragma unroll
    for (int j = 0; j < 4; j++) acc[i][j] = (f32x4){0.f, 0.f, 0.f, 0.f};
  int srow = tid >> 2;
  int scol = (tid & 3) * 8;
  for (int kt = 0; kt < 32; kt++) {
    int k0 = kt * 32;
    __syncthreads();
    gload_lds16(Xb + (size_t)(m0 + srow) * 1024 + k0 + scol, As + srow * 32 + scol);
    gload_lds16(Xb + (size_t)(m0 + 64 + srow) * 1024 + k0 + scol, As + (64 + srow) * 32 + scol);
    gload_lds16(Wb + (size_t)(n0 + srow) * 1024 + k0 + scol, Bs + srow * 32 + scol);
    gload_lds16(Wb + (size_t)(n0 + 64 + srow) * 1024 + k0 + scol, Bs + (64 + srow) * 32 + scol);
    asm volatile("s_waitcnt vmcnt(0)" ::: "memory");
    __syncthreads();
    short8 a[4], b[4];
#pragma unroll
    for (int i = 0; i < 4; i++) a[i] = *(const short8*)(As + (wr * 64 + i * 16 + lo) * 32 + hi * 8);
#pragma unroll
    for (int i = 0; i < 4; i++) b[i] = *(const short8*)(Bs + (wc * 64 + i * 16 + lo) * 32 + hi * 8);
#pragma unroll
    for (int i = 0; i < 4; i++)
#pragma unroll
      for (int j = 0; j < 4; j++) acc[i][j] = mfma16(a[i], b[j], acc[i][j]);
  }
#pragma unroll
  for (int i = 0; i < 4; i++)
#pragma unroll
    for (int j = 0; j < 4; j++)
#pragma unroll
      for (int e = 0; e < 4; e++) {
        int r = m0 + wr * 64 + i * 16 + hi * 4 + e;
        int c = n0 + wc * 64 + j * 16 + lo;
        float v = acc[i][j][e] + E[(size_t)(r & 63) * G3 + c];
        gi[(size_t)r * G3 + c] = f2bf(v);
      }
}

// ---------------- persistent recurrence kernel ----------------
// 64 wgs x 1024 thr. wg cs owns h cols [cs*16,+16). 16 waves: rt = w&3, kq = w>>2.
// Updaters = kq==0 (waves 0-3). Wave 15 polls.
// Mailbox-matrix barrier, ZERO shared lines, ZERO RMWs:
//   mbox[reader][writer_wg*4 + writer_rt] : uint = 1 + last published step.
//   Updater wave rt of wg cs: after draining ITS OWN h-stores (vmcnt(0)),
//   lane l relaxed-stores (t+2) to mbox[l][cs*4+rt]  (64 readers, 1 inst).
//   Poller (wave 15) lane l reads its OWN row's 16B for writer-wg l
//   (4 cells, rt 0..3) -> each mbox line has exactly 1 writer + 1 reader.
__global__ __launch_bounds__(1024) void k_rnn(
    const unsigned short* __restrict__ giE,   // [256*64][3072] bf16 (incl E)
    const unsigned short* __restrict__ Whhb,  // [3072][1024] bf16
    const float* __restrict__ b_hh,
    const float* __restrict__ h0,
    const int* __restrict__ length,
    unsigned short* __restrict__ hbuf,        // [2][64][1024] bf16
    float* __restrict__ out,                  // [256][64][1024] f32
    float* __restrict__ hn,                   // [64][1024] f32
    unsigned int* __restrict__ mbox) {        // [64 readers][256] uints (1KB rows)
  __shared__ f32x4 red[16 * 3 * 64];          // 48 KB
  __shared__ float hp0[2][16];
  const int cs = blockIdx.x;
  const int j0 = cs * 16;
  const int tid = threadIdx.x;
  const int w = tid >> 6, l = tid & 63, lo = l & 15, hi = l >> 4;
  const int rt = w & 3, kq = w >> 2;
  const bool upd = (kq == 0);
  const int col = j0 + lo;
  const int rowbase = rt * 16;

  const unsigned short* wrp0 = Whhb + (size_t)col * 1024;
  const unsigned short* wrp1 = Whhb + (size_t)(1024 + col) * 1024;
  const unsigned short* wrp2 = Whhb + (size_t)(2048 + col) * 1024;
  const float bhhn = b_hh[2048 + col];

  float hown[4] = {0.f, 0.f, 0.f, 0.f};
  float gir[3][4], girN[3][4];
  int len4[4] = {0, 0, 0, 0};

  // ---- init: load h0 state, publish h(0), per-wave drain + signal V=1 ----
  if (upd) {
#pragma unroll
    for (int j = 0; j < 4; j++) {
      int b = rowbase + hi * 4 + j;
      hown[j] = h0[(size_t)b * 1024 + col];
      len4[j] = length[b];
    }
#pragma unroll
    for (int j = 0; j < 4; j++) {
      unsigned int mine = f2bf(hown[j]);
      unsigned int oth = __shfl_xor(mine, 1, 64);
      if (!(lo & 1)) {
        int b = rowbase + hi * 4 + j;
        __hip_atomic_store((unsigned int*)(hbuf + (size_t)b * 1024 + j0 + lo),
                           mine | (oth << 16), __ATOMIC_RELAXED, __HIP_MEMORY_SCOPE_AGENT);
      }
    }
    if (rt == 0 && hi == 0) hp0[0][lo] = hown[0];
    asm volatile("s_waitcnt vmcnt(0)" ::: "memory");
    __hip_atomic_store(&mbox[(size_t)l * 256 + cs * 4 + rt], 1u,
                       __ATOMIC_RELAXED, __HIP_MEMORY_SCOPE_AGENT);
#pragma unroll
    for (int s = 0; s < 3; s++)
#pragma unroll
      for (int j = 0; j < 4; j++)
        gir[s][j] = bf2f(giE[(size_t)(rowbase + hi * 4 + j) * G3 + s * 1024 + col]);
  }

  for (int t = 0; t < TT; t++) {
    // ---- A: overlap window (stores/prefetch off the critical path) ----
    if (upd) {
      if (t > 0) {
#pragma unroll
        for (int j = 0; j < 4; j++) {
          int b = rowbase + hi * 4 + j;
          out[(size_t)(t - 1) * (BB * HH) + (size_t)b * 1024 + col] = hown[j];
        }
      }
      if (t < TT - 1) {
        const unsigned short* gb = giE + (size_t)(t + 1) * 64 * G3;
#pragma unroll
        for (int s = 0; s < 3; s++)
#pragma unroll
          for (int j = 0; j < 4; j++)
            girN[s][j] = bf2f(gb[(size_t)(rowbase + hi * 4 + j) * G3 + s * 1024 + col]);
      }
    }
    // ---- B: poller wave scans its private mailbox row (contention-free) ----
    if (w == 15) {
      const ull* cb = (const ull*)(mbox + (size_t)cs * 256 + l * 4);
      unsigned int tgt = (unsigned int)(t + 1);
      for (;;) {
        ull u0 = __hip_atomic_load(cb, __ATOMIC_RELAXED, __HIP_MEMORY_SCOPE_AGENT);
        ull u1 = __hip_atomic_load(cb + 1, __ATOMIC_RELAXED, __HIP_MEMORY_SCOPE_AGENT);
        bool ok = ((unsigned int)u0 >= tgt) && ((unsigned int)(u0 >> 32) >= tgt) &&
                  ((unsigned int)u1 >= tgt) && ((unsigned int)(u1 >> 32) >= tgt);
        if (__all(ok)) break;
        __builtin_amdgcn_s_sleep(1);
      }
    }
    __syncthreads();
    // ---- C: partial GEMM on h(t) ----
    const unsigned short* hb = hbuf + (size_t)(t & 1) * (BB * 1024);
    f32x4 a0 = {0.f, 0.f, 0.f, 0.f}, a1 = a0, a2 = a0;
#pragma unroll
    for (int kk = 0; kk < 8; kk++) {
      int k = kq * 256 + kk * 32 + hi * 8;
      const unsigned short* hp = hb + (size_t)(rowbase + lo) * 1024 + k;
      union { ull u[2]; short8 v; } a;
      a.u[0] = __hip_atomic_load((const ull*)hp, __ATOMIC_RELAXED, __HIP_MEMORY_SCOPE_AGENT);
      a.u[1] = __hip_atomic_load((const ull*)(hp + 4), __ATOMIC_RELAXED, __HIP_MEMORY_SCOPE_AGENT);
      short8 b0 = *(const short8*)(wrp0 + k);
      short8 b1 = *(const short8*)(wrp1 + k);
      short8 b2 = *(const short8*)(wrp2 + k);
      a0 = mfma16(a.v, b0, a0);
      a1 = mfma16(a.v, b1, a1);
      a2 = mfma16(a.v, b2, a2);
    }
    red[(w * 3 + 0) * 64 + l] = a0;
    red[(w * 3 + 1) * 64 + l] = a1;
    red[(w * 3 + 2) * 64 + l] = a2;
    __syncthreads();
    // ---- D: updaters reduce + gates + publish h(t+1) + early per-wave signal ----
    if (upd) {
      float h0p = hp0[t & 1][lo];
      f32x4 fin[3];
#pragma unroll
      for (int s = 0; s < 3; s++) {
        f32x4 v = red[((0 * 4 + rt) * 3 + s) * 64 + l];
#pragma unroll
        for (int kq2 = 1; kq2 < 4; kq2++) {
          f32x4 p = red[((kq2 * 4 + rt) * 3 + s) * 64 + l];
          v[0] += p[0]; v[1] += p[1]; v[2] += p[2]; v[3] += p[3];
        }
        fin[s] = v;
      }
      float hv[4];
#pragma unroll
      for (int j = 0; j < 4; j++) {
        float R = fin[0][j] + gir[0][j];
        float I = fin[1][j] + gir[1][j];
        float rg = 1.f / (1.f + __expf(-R));
        float ig = 1.f / (1.f + __expf(-I));
        float nx = gir[2][j] + rg * (fin[2][j] + bhhn);
        nx = fminf(15.f, fmaxf(-15.f, nx));
        float e2 = __expf(2.f * nx);
        float ng = (e2 - 1.f) / (e2 + 1.f);
        float hy = ng + ig * (hown[j] - ng);
        float res = (t < len4[j]) ? hy : h0p;
        hv[j] = res;
        hown[j] = res;
      }
      if (t < TT - 1) {
        unsigned short* dst = hbuf + (size_t)((t + 1) & 1) * (BB * 1024);
#pragma unroll
        for (int j = 0; j < 4; j++) {
          unsigned int mine = f2bf(hv[j]);
          unsigned int oth = __shfl_xor(mine, 1, 64);
          if (!(lo & 1)) {
            int b = rowbase + hi * 4 + j;
            __hip_atomic_store((unsigned int*)(dst + (size_t)b * 1024 + j0 + lo),
                               mine | (oth << 16), __ATOMIC_RELAXED, __HIP_MEMORY_SCOPE_AGENT);
          }
        }
        if (rt == 0 && hi == 0) hp0[(t + 1) & 1][lo] = hv[0];
        // drain OWN h-stores, then signal all 64 readers (1 store inst, 64 lines)
        asm volatile("s_waitcnt vmcnt(0)" ::: "memory");
        __hip_atomic_store(&mbox[(size_t)l * 256 + cs * 4 + rt], (unsigned int)(t + 2),
                           __ATOMIC_RELAXED, __HIP_MEMORY_SCOPE_AGENT);
        // register handoff for next iter
#pragma unroll
        for (int s = 0; s < 3; s++)
#pragma unroll
          for (int j = 0; j < 4; j++)
            gir[s][j] = girN[s][j];
      }
    }
    __syncthreads();   // rejoin; red[] reuse next iter is safe after this
  }
  // ---- tail: out(TT-1) + hn ----
  if (upd) {
#pragma unroll
    for (int j = 0; j < 4; j++) {
      int b = rowbase + hi * 4 + j;
      out[(size_t)(TT - 1) * (BB * HH) + (size_t)b * 1024 + col] = hown[j];
      hn[(size_t)b * 1024 + col] = hown[j];
    }
  }
}

// ---------------- host ----------------
extern "C" void kernel_launch(void* const* d_in, const int* in_sizes, int n_in,
                              void* d_out, int out_size, void* d_ws, size_t ws_size,
                              hipStream_t stream) {
  const float* input_ = (const float*)d_in[0];
  const int* length   = (const int*)d_in[1];
  const float* h0     = (const float*)d_in[2];
  const float* cj     = (const float*)d_in[3];
  const float* he     = (const float*)d_in[4];
  const float* w_ih   = (const float*)d_in[5];
  const float* w_hh   = (const float*)d_in[6];
  const float* w_ch   = (const float*)d_in[7];
  const float* w_zh   = (const float*)d_in[8];
  const float* b_ih   = (const float*)d_in[9];
  const float* b_hh   = (const float*)d_in[10];
  const float* b_ch   = (const float*)d_in[11];
  const float* b_zh   = (const float*)d_in[12];

  char* ws = (char*)d_ws;
  const size_t OFF_MBOX  = 0;              // 65536 B: [64][256] uints
  const size_t OFF_XB    = 131072;
  const size_t OFF_WIHB  = OFF_XB + 33554432ull;
  const size_t OFF_WHHB  = OFF_WIHB + 6291456ull;
  const size_t OFF_WCHB  = OFF_WHHB + 6291456ull;
  const size_t OFF_WZHB  = OFF_WCHB + 6291456ull;
  const size_t OFF_CJB   = OFF_WZHB + 6291456ull;
  const size_t OFF_HEB   = OFF_CJB + 131072ull;
  const size_t OFF_E     = OFF_HEB + 131072ull;
  const size_t OFF_GI    = OFF_E + 786432ull;
  const size_t OFF_HBUF  = OFF_GI + 100663296ull;

  unsigned int* mbox    = (unsigned int*)(ws + OFF_MBOX);
  unsigned short* Xb    = (unsigned short*)(ws + OFF_XB);
  unsigned short* Wihb  = (unsigned short*)(ws + OFF_WIHB);
  unsigned short* Whhb  = (unsigned short*)(ws + OFF_WHHB);
  unsigned short* Wchb  = (unsigned short*)(ws + OFF_WCHB);
  unsigned short* Wzhb  = (unsigned short*)(ws + OFF_WZHB);
  unsigned short* cjb   = (unsigned short*)(ws + OFF_CJB);
  unsigned short* heb   = (unsigned short*)(ws + OFF_HEB);
  float* E              = (float*)(ws + OFF_E);
  unsigned short* gi    = (unsigned short*)(ws + OFF_GI);
  unsigned short* hbuf  = (unsigned short*)(ws + OFF_HBUF);

  float* out = (float*)d_out;
  float* hn  = out + 16777216;   // T*B*H

  hipMemsetAsync(mbox, 0, 65536, stream);
  k_cvt_bf16<<<2048, 256, 0, stream>>>(input_, Xb, 16777216 / 4);
  k_cvt_bf16<<<1024, 256, 0, stream>>>(w_ih, Wihb, 3145728 / 4);
  k_cvt_bf16<<<1024, 256, 0, stream>>>(w_hh, Whhb, 3145728 / 4);
  k_cvt_bf16<<<1024, 256, 0, stream>>>(w_ch, Wchb, 3145728 / 4);
  k_cvt_bf16<<<1024, 256, 0, stream>>>(w_zh, Wzhb, 3145728 / 4);
  k_cvt_bf16<<<64, 256, 0, stream>>>(cj, cjb, 65536 / 4);
  k_cvt_bf16<<<64, 256, 0, stream>>>(he, heb, 65536 / 4);
  k_ctx<<<192, 256, 0, stream>>>(cjb, heb, Wchb, Wzhb, b_ih, b_hh, b_ch, b_zh, E);
  k_gemm_gi<<<3072, 256, 0, stream>>>(Xb, Wihb, E, gi);
  k_rnn<<<64, 1024, 0, stream>>>(gi, Whhb, b_hh, h0, length, hbuf, out, hn, mbox);
}

// Round 6
// 1862.318 us; speedup vs baseline: 2.1584x; 2.1584x over previous
//
#include <hip/hip_runtime.h>
#include <stdint.h>

#define TT 256
#define BB 64
#define DD 1024
#define HH 1024
#define G3 3072

typedef unsigned long long ull;
typedef __attribute__((ext_vector_type(8))) short short8;
typedef __attribute__((ext_vector_type(4))) float f32x4;

__device__ __forceinline__ unsigned short f2bf(float f) {
  union { float f; unsigned int i; } v; v.f = f;
  unsigned int x = v.i;
  return (unsigned short)((x + 0x7fffu + ((x >> 16) & 1u)) >> 16);
}
__device__ __forceinline__ float bf2f(unsigned short u) {
  union { unsigned int i; float f; } v; v.i = ((unsigned int)u) << 16; return v.f;
}
__device__ __forceinline__ f32x4 mfma16(short8 a, short8 b, f32x4 c) {
  return __builtin_amdgcn_mfma_f32_16x16x32_bf16(a, b, c, 0, 0, 0);
}
__device__ __forceinline__ void gload_lds16(const void* g, void* l) {
  __builtin_amdgcn_global_load_lds((const __attribute__((address_space(1))) void*)g,
                                   (__attribute__((address_space(3))) void*)l,
                                   16, 0, 0);
}

// ---------------- f32 -> bf16 convert (vectorized) ----------------
__global__ void k_cvt_bf16(const float* __restrict__ in, unsigned short* __restrict__ out, int n4) {
  int i = blockIdx.x * blockDim.x + threadIdx.x;
  int stride = gridDim.x * blockDim.x;
  for (; i < n4; i += stride) {
    float4 v = ((const float4*)in)[i];
    ushort4 o;
    o.x = f2bf(v.x); o.y = f2bf(v.y); o.z = f2bf(v.z); o.w = f2bf(v.w);
    ((ushort4*)out)[i] = o;
  }
}

// ---------------- context projections + bias fold: E[64][3072] ----------------
__global__ __launch_bounds__(256) void k_ctx(
    const unsigned short* __restrict__ cjb, const unsigned short* __restrict__ heb,
    const unsigned short* __restrict__ Wchb, const unsigned short* __restrict__ Wzhb,
    const float* __restrict__ b_ih, const float* __restrict__ b_hh,
    const float* __restrict__ b_ch, const float* __restrict__ b_zh,
    float* __restrict__ E) {
  __shared__ f32x4 red[4][4][64];   // 16 KB
  int n0 = blockIdx.x * 16;         // 192 blocks
  int tid = threadIdx.x;
  int w = tid >> 6, l = tid & 63, lo = l & 15, hi = l >> 4;
  f32x4 acc[4];
#pragma unroll
  for (int r = 0; r < 4; r++) acc[r] = (f32x4){0.f, 0.f, 0.f, 0.f};
#pragma unroll 4
  for (int kk = 0; kk < 16; kk++) {
    int k = w * 512 + kk * 32;
    const unsigned short* Asrc = (k < 1024) ? cjb : heb;
    const unsigned short* Bsrc = (k < 1024) ? Wchb : Wzhb;
    int kw = (k < 1024) ? k : (k - 1024);
    int kof = kw + hi * 8;
    short8 bf = *(const short8*)(Bsrc + (size_t)(n0 + lo) * 1024 + kof);
#pragma unroll
    for (int r = 0; r < 4; r++) {
      short8 af = *(const short8*)(Asrc + (size_t)(r * 16 + lo) * 1024 + kof);
      acc[r] = mfma16(af, bf, acc[r]);
    }
  }
#pragma unroll
  for (int r = 0; r < 4; r++) red[w][r][l] = acc[r];
  __syncthreads();
  f32x4 s = red[0][w][l];
#pragma unroll
  for (int w2 = 1; w2 < 4; w2++) {
    f32x4 p = red[w2][w][l];
    s[0] += p[0]; s[1] += p[1]; s[2] += p[2]; s[3] += p[3];
  }
  int g = n0 + lo;
  float bias = b_ih[g] + b_ch[g] + b_zh[g] + ((g < 2048) ? b_hh[g] : 0.0f);
#pragma unroll
  for (int j = 0; j < 4; j++) {
    int b = w * 16 + hi * 4 + j;
    E[(size_t)b * G3 + g] = s[j] + bias;
  }
}

// ---------------- gi GEMM + E fold: giE[t*64+b][g] = X@Wih^T + E[b][g] (bf16) --------
__global__ __launch_bounds__(256) void k_gemm_gi(
    const unsigned short* __restrict__ Xb,   // [16384][1024] bf16
    const unsigned short* __restrict__ Wb,   // [3072][1024] bf16
    const float* __restrict__ E,             // [64][3072] f32
    unsigned short* __restrict__ gi) {       // [16384][3072] bf16
  __shared__ unsigned short As[128 * 32];
  __shared__ unsigned short Bs[128 * 32];
  int bid = blockIdx.x;
  int mt = bid & 127;
  int nt = bid >> 7;
  int m0 = mt * 128, n0 = nt * 128;
  int tid = threadIdx.x;
  int w = tid >> 6, l = tid & 63, lo = l & 15, hi = l >> 4;
  int wr = w >> 1, wc = w & 1;
  f32x4 acc[4][4];
#pragma unroll
  for (int i = 0; i < 4; i++)
#pragma unroll
    for (int j = 0; j < 4; j++) acc[i][j] = (f32x4){0.f, 0.f, 0.f, 0.f};
  int srow = tid >> 2;
  int scol = (tid & 3) * 8;
  for (int kt = 0; kt < 32; kt++) {
    int k0 = kt * 32;
    __syncthreads();
    gload_lds16(Xb + (size_t)(m0 + srow) * 1024 + k0 + scol, As + srow * 32 + scol);
    gload_lds16(Xb + (size_t)(m0 + 64 + srow) * 1024 + k0 + scol, As + (64 + srow) * 32 + scol);
    gload_lds16(Wb + (size_t)(n0 + srow) * 1024 + k0 + scol, Bs + srow * 32 + scol);
    gload_lds16(Wb + (size_t)(n0 + 64 + srow) * 1024 + k0 + scol, Bs + (64 + srow) * 32 + scol);
    asm volatile("s_waitcnt vmcnt(0)" ::: "memory");
    __syncthreads();
    short8 a[4], b[4];
#pragma unroll
    for (int i = 0; i < 4; i++) a[i] = *(const short8*)(As + (wr * 64 + i * 16 + lo) * 32 + hi * 8);
#pragma unroll
    for (int i = 0; i < 4; i++) b[i] = *(const short8*)(Bs + (wc * 64 + i * 16 + lo) * 32 + hi * 8);
#pragma unroll
    for (int i = 0; i < 4; i++)
#pragma unroll
      for (int j = 0; j < 4; j++) acc[i][j] = mfma16(a[i], b[j], acc[i][j]);
  }
#pragma unroll
  for (int i = 0; i < 4; i++)
#pragma unroll
    for (int j = 0; j < 4; j++)
#pragma unroll
      for (int e = 0; e < 4; e++) {
        int r = m0 + wr * 64 + i * 16 + hi * 4 + e;
        int c = n0 + wc * 64 + j * 16 + lo;
        float v = acc[i][j][e] + E[(size_t)(r & 63) * G3 + c];
        gi[(size_t)r * G3 + c] = f2bf(v);
      }
}

// ---------------- barrier probe: pure all-to-all store->poll ping-pong ----------------
__global__ __launch_bounds__(256) void k_probe(unsigned int* __restrict__ ps) {
  int wg = blockIdx.x;
  int tid = threadIdx.x;
  int l = tid & 63;
  for (int t = 0; t < TT; ++t) {
    if (tid == 0)
      __hip_atomic_store(&ps[wg * 16], (unsigned)(t + 1), __ATOMIC_RELAXED, __HIP_MEMORY_SCOPE_AGENT);
    if (tid < 64) {
      for (;;) {
        unsigned v = __hip_atomic_load(&ps[l * 16], __ATOMIC_RELAXED, __HIP_MEMORY_SCOPE_AGENT);
        if (__all(v >= (unsigned)(t + 1))) break;
        __builtin_amdgcn_s_sleep(1);
      }
    }
    __syncthreads();
  }
}

// ---------------- persistent recurrence kernel (v6) ----------------
// 64 wgs x 1024 thr. wg cs owns h cols [cs*16,+16). 16 waves: rt=w&3, kq=w>>2.
// Whh slice pre-swizzled into LDS (96 KB, conflict-free ds_read_b128).
// h exchange in transposed block layout hbuf[slot][colblock64][row64][col16] bf16:
//   writer wave (cs,rt) writes its 512B run; reader reads dense 512B runs.
// Sync: seq[cs][rt] words; each wave polls only its 16 producers. ONE syncthreads
// per step (red WAR across steps is implied by poll: seq>=t+2 => updater read red(t)).
__global__ __launch_bounds__(1024) void k_rnn(
    const unsigned short* __restrict__ giE,   // [256*64][3072] bf16 (incl E)
    const unsigned short* __restrict__ Whhb,  // [3072][1024] bf16
    const float* __restrict__ b_hh,
    const float* __restrict__ h0,
    const int* __restrict__ length,
    unsigned short* __restrict__ hbuf,        // [2][64][64][16] bf16 (transposed blocks)
    float* __restrict__ out,                  // [256][64][1024] f32
    float* __restrict__ hn,                   // [64][1024] f32
    unsigned int* __restrict__ seq) {         // [64 cs][4 rt] words, 64B-spaced
  extern __shared__ char smem[];
  unsigned short* wlds = (unsigned short*)smem;              // 96 KB: [96 frags][64 lanes][8]
  f32x4* red = (f32x4*)(smem + 98304);                       // 48 KB: [16 waves][3 strips][64]
  float* hp0 = (float*)(smem + 98304 + 49152);               // [2][16]

  const int cs = blockIdx.x;
  const int j0 = cs * 16;
  const int tid = threadIdx.x;
  const int w = tid >> 6, l = tid & 63, lo = l & 15, hi = l >> 4;
  const int rt = w & 3, kq = w >> 2;
  const bool upd = (kq == 0);
  const int col = j0 + lo;
  const int rowbase = rt * 16;

  const float bhhn = b_hh[2048 + col];
  float hown[4] = {0.f, 0.f, 0.f, 0.f};
  float gir[3][4];
  int len4[4] = {0, 0, 0, 0};

  // ---- weight preload into LDS, pre-swizzled to fragment order ----
  // frag f=(kq*8+kk)*3+s, lane l holds W[s*1024+j0+lo][kq*256+kk*32+hi*8 .. +8]
  if (rt == 0) {
#pragma unroll
    for (int kk = 0; kk < 8; ++kk)
#pragma unroll
      for (int s = 0; s < 3; ++s) {
        int f = (kq * 8 + kk) * 3 + s;
        short8 v = *(const short8*)(Whhb + (size_t)(s * 1024 + j0 + lo) * 1024 + kq * 256 + kk * 32 + hi * 8);
        ((short8*)wlds)[f * 64 + l] = v;
      }
  }
  // ---- init: h0 state, publish h(0) transposed, hp0 ----
  if (upd) {
#pragma unroll
    for (int j = 0; j < 4; j++) {
      int b = rowbase + hi * 4 + j;
      hown[j] = h0[(size_t)b * 1024 + col];
      len4[j] = length[b];
    }
#pragma unroll
    for (int j = 0; j < 4; j++) {
      unsigned int mine = f2bf(hown[j]);
      unsigned int oth = __shfl_xor(mine, 1, 64);
      if (!(lo & 1)) {
        int row = rowbase + hi * 4 + j;
        __hip_atomic_store((unsigned int*)(hbuf + (size_t)cs * 1024 + row * 16 + lo),
                           mine | (oth << 16), __ATOMIC_RELAXED, __HIP_MEMORY_SCOPE_AGENT);
      }
    }
    if (rt == 0 && hi == 0) hp0[lo] = hown[0];
  }
  __syncthreads();   // wlds + hp0 ready; drains vmem
  if (upd) {
    asm volatile("s_waitcnt vmcnt(0)" ::: "memory");
    if (l == 0)
      __hip_atomic_store(&seq[(cs * 4 + rt) * 16], 1u, __ATOMIC_RELAXED, __HIP_MEMORY_SCOPE_AGENT);
#pragma unroll
    for (int s = 0; s < 3; s++)
#pragma unroll
      for (int j = 0; j < 4; j++)
        gir[s][j] = bf2f(giE[(size_t)(rowbase + hi * 4 + j) * G3 + s * 1024 + col]);
  }

  for (int t = 0; t < TT; t++) {
    // ---- poll my 16 producers: wgs kq*16..+15, wave rt ----
    {
      const unsigned int* sp = seq + ((size_t)(kq * 16 + lo) * 4 + rt) * 16;
      unsigned int tgt = (unsigned int)(t + 1);
      for (;;) {
        unsigned int v = __hip_atomic_load(sp, __ATOMIC_RELAXED, __HIP_MEMORY_SCOPE_AGENT);
        if (__all(v >= tgt)) break;
        __builtin_amdgcn_s_sleep(1);
      }
    }
    // ---- C: partial GEMM on h(t); h from transposed blocks, W from LDS ----
    const unsigned short* hb2 = hbuf + ((size_t)(t & 1) << 16);
    f32x4 a0 = {0.f, 0.f, 0.f, 0.f}, a1 = a0, a2 = a0;
#pragma unroll
    for (int kk = 0; kk < 8; kk++) {
      int k = kq * 256 + kk * 32;
      int blk = (k >> 4) + (hi >> 1);
      const unsigned short* hp = hb2 + (size_t)blk * 1024 + (rowbase + lo) * 16 + (hi & 1) * 8;
      union { ull u[2]; short8 v; } a;
      a.u[0] = __hip_atomic_load((const ull*)hp, __ATOMIC_RELAXED, __HIP_MEMORY_SCOPE_AGENT);
      a.u[1] = __hip_atomic_load((const ull*)hp + 1, __ATOMIC_RELAXED, __HIP_MEMORY_SCOPE_AGENT);
      const short8* wf = ((const short8*)wlds) + (size_t)((kq * 8 + kk) * 3) * 64 + l;
      short8 b0 = wf[0];
      short8 b1 = wf[64];
      short8 b2 = wf[128];
      a0 = mfma16(a.v, b0, a0);
      a1 = mfma16(a.v, b1, a1);
      a2 = mfma16(a.v, b2, a2);
    }
    red[(w * 3 + 0) * 64 + l] = a0;
    red[(w * 3 + 1) * 64 + l] = a1;
    red[(w * 3 + 2) * 64 + l] = a2;
    __syncthreads();   // the ONE barrier per step
    // ---- D: updaters reduce + gates + publish + post ----
    if (upd) {
      float h0p = hp0[(t & 1) * 16 + lo];
      f32x4 fin[3];
#pragma unroll
      for (int s = 0; s < 3; s++) {
        f32x4 v = red[((0 * 4 + rt) * 3 + s) * 64 + l];
#pragma unroll
        for (int kq2 = 1; kq2 < 4; kq2++) {
          f32x4 p = red[((kq2 * 4 + rt) * 3 + s) * 64 + l];
          v[0] += p[0]; v[1] += p[1]; v[2] += p[2]; v[3] += p[3];
        }
        fin[s] = v;
      }
      float hv[4];
#pragma unroll
      for (int j = 0; j < 4; j++) {
        float R = fin[0][j] + gir[0][j];
        float I = fin[1][j] + gir[1][j];
        float rg = 1.f / (1.f + __expf(-R));
        float ig = 1.f / (1.f + __expf(-I));
        float nx = gir[2][j] + rg * (fin[2][j] + bhhn);
        nx = fminf(15.f, fmaxf(-15.f, nx));
        float e2 = __expf(2.f * nx);
        float ng = (e2 - 1.f) / (e2 + 1.f);
        float hy = ng + ig * (hown[j] - ng);
        float res = (t < len4[j]) ? hy : h0p;
        hv[j] = res;
        hown[j] = res;
      }
      if (t < TT - 1) {
        unsigned short* dst = hbuf + ((size_t)((t + 1) & 1) << 16) + (size_t)cs * 1024;
#pragma unroll
        for (int j = 0; j < 4; j++) {
          unsigned int mine = f2bf(hv[j]);
          unsigned int oth = __shfl_xor(mine, 1, 64);
          if (!(lo & 1)) {
            int row = rowbase + hi * 4 + j;
            __hip_atomic_store((unsigned int*)(dst + row * 16 + lo),
                               mine | (oth << 16), __ATOMIC_RELAXED, __HIP_MEMORY_SCOPE_AGENT);
          }
        }
        if (rt == 0 && hi == 0) hp0[(((t + 1) & 1)) * 16 + lo] = hv[0];
        asm volatile("s_waitcnt vmcnt(0)" ::: "memory");
        if (l == 0)
          __hip_atomic_store(&seq[(cs * 4 + rt) * 16], (unsigned int)(t + 2),
                             __ATOMIC_RELAXED, __HIP_MEMORY_SCOPE_AGENT);
      }
      // off-critical-path work after the post
#pragma unroll
      for (int j = 0; j < 4; j++) {
        int b = rowbase + hi * 4 + j;
        out[(size_t)t * (BB * HH) + (size_t)b * 1024 + col] = hv[j];
      }
      if (t == TT - 1) {
#pragma unroll
        for (int j = 0; j < 4; j++) {
          int b = rowbase + hi * 4 + j;
          hn[(size_t)b * 1024 + col] = hv[j];
        }
      } else {
        const unsigned short* gb = giE + (size_t)(t + 1) * 64 * G3;
#pragma unroll
        for (int s = 0; s < 3; s++)
#pragma unroll
          for (int j = 0; j < 4; j++)
            gir[s][j] = bf2f(gb[(size_t)(rowbase + hi * 4 + j) * G3 + s * 1024 + col]);
      }
    }
  }
}

// ---------------- host ----------------
extern "C" void kernel_launch(void* const* d_in, const int* in_sizes, int n_in,
                              void* d_out, int out_size, void* d_ws, size_t ws_size,
                              hipStream_t stream) {
  const float* input_ = (const float*)d_in[0];
  const int* length   = (const int*)d_in[1];
  const float* h0     = (const float*)d_in[2];
  const float* cj     = (const float*)d_in[3];
  const float* he     = (const float*)d_in[4];
  const float* w_ih   = (const float*)d_in[5];
  const float* w_hh   = (const float*)d_in[6];
  const float* w_ch   = (const float*)d_in[7];
  const float* w_zh   = (const float*)d_in[8];
  const float* b_ih   = (const float*)d_in[9];
  const float* b_hh   = (const float*)d_in[10];
  const float* b_ch   = (const float*)d_in[11];
  const float* b_zh   = (const float*)d_in[12];

  char* ws = (char*)d_ws;
  const size_t OFF_SEQ   = 0;              // 16 KB: [64][4] words, 64B-spaced
  const size_t OFF_PROBE = 16384;          // 4 KB
  const size_t OFF_XB    = 131072;
  const size_t OFF_WIHB  = OFF_XB + 33554432ull;
  const size_t OFF_WHHB  = OFF_WIHB + 6291456ull;
  const size_t OFF_WCHB  = OFF_WHHB + 6291456ull;
  const size_t OFF_WZHB  = OFF_WCHB + 6291456ull;
  const size_t OFF_CJB   = OFF_WZHB + 6291456ull;
  const size_t OFF_HEB   = OFF_CJB + 131072ull;
  const size_t OFF_E     = OFF_HEB + 131072ull;
  const size_t OFF_GI    = OFF_E + 786432ull;
  const size_t OFF_HBUF  = OFF_GI + 100663296ull;

  unsigned int* seq     = (unsigned int*)(ws + OFF_SEQ);
  unsigned int* probe   = (unsigned int*)(ws + OFF_PROBE);
  unsigned short* Xb    = (unsigned short*)(ws + OFF_XB);
  unsigned short* Wihb  = (unsigned short*)(ws + OFF_WIHB);
  unsigned short* Whhb  = (unsigned short*)(ws + OFF_WHHB);
  unsigned short* Wchb  = (unsigned short*)(ws + OFF_WCHB);
  unsigned short* Wzhb  = (unsigned short*)(ws + OFF_WZHB);
  unsigned short* cjb   = (unsigned short*)(ws + OFF_CJB);
  unsigned short* heb   = (unsigned short*)(ws + OFF_HEB);
  float* E              = (float*)(ws + OFF_E);
  unsigned short* gi    = (unsigned short*)(ws + OFF_GI);
  unsigned short* hbuf  = (unsigned short*)(ws + OFF_HBUF);

  float* out = (float*)d_out;
  float* hn  = out + 16777216;   // T*B*H

  static int lds_set = 0;
  if (!lds_set) {
    hipFuncSetAttribute((const void*)k_rnn, hipFuncAttributeMaxDynamicSharedMemorySize, 147712);
    lds_set = 1;
  }

  hipMemsetAsync(ws, 0, 32768, stream);   // seq + probe
  k_cvt_bf16<<<2048, 256, 0, stream>>>(input_, Xb, 16777216 / 4);
  k_cvt_bf16<<<1024, 256, 0, stream>>>(w_ih, Wihb, 3145728 / 4);
  k_cvt_bf16<<<1024, 256, 0, stream>>>(w_hh, Whhb, 3145728 / 4);
  k_cvt_bf16<<<1024, 256, 0, stream>>>(w_ch, Wchb, 3145728 / 4);
  k_cvt_bf16<<<1024, 256, 0, stream>>>(w_zh, Wzhb, 3145728 / 4);
  k_cvt_bf16<<<64, 256, 0, stream>>>(cj, cjb, 65536 / 4);
  k_cvt_bf16<<<64, 256, 0, stream>>>(he, heb, 65536 / 4);
  k_ctx<<<192, 256, 0, stream>>>(cjb, heb, Wchb, Wzhb, b_ih, b_hh, b_ch, b_zh, E);
  k_gemm_gi<<<3072, 256, 0, stream>>>(Xb, Wihb, E, gi);
  k_probe<<<64, 256, 0, stream>>>(probe);
  k_rnn<<<64, 1024, 147712, stream>>>(gi, Whhb, b_hh, h0, length, hbuf, out, hn, seq);
}

// Round 7
// 1454.222 us; speedup vs baseline: 2.7642x; 1.2806x over previous
//
#include <hip/hip_runtime.h>
#include <stdint.h>

#define TT 256
#define BB 64
#define DD 1024
#define HH 1024
#define G3 3072

typedef unsigned long long ull;
typedef __attribute__((ext_vector_type(8))) short short8;
typedef __attribute__((ext_vector_type(4))) float f32x4;

__device__ __forceinline__ unsigned short f2bf(float f) {
  union { float f; unsigned int i; } v; v.f = f;
  unsigned int x = v.i;
  return (unsigned short)((x + 0x7fffu + ((x >> 16) & 1u)) >> 16);
}
__device__ __forceinline__ float bf2f(unsigned short u) {
  union { unsigned int i; float f; } v; v.i = ((unsigned int)u) << 16; return v.f;
}
__device__ __forceinline__ f32x4 mfma16(short8 a, short8 b, f32x4 c) {
  return __builtin_amdgcn_mfma_f32_16x16x32_bf16(a, b, c, 0, 0, 0);
}
__device__ __forceinline__ void gload_lds16(const void* g, void* l) {
  __builtin_amdgcn_global_load_lds((const __attribute__((address_space(1))) void*)g,
                                   (__attribute__((address_space(3))) void*)l,
                                   16, 0, 0);
}

// ---------------- f32 -> bf16 convert (vectorized) ----------------
__global__ void k_cvt_bf16(const float* __restrict__ in, unsigned short* __restrict__ out, int n4) {
  int i = blockIdx.x * blockDim.x + threadIdx.x;
  int stride = gridDim.x * blockDim.x;
  for (; i < n4; i += stride) {
    float4 v = ((const float4*)in)[i];
    ushort4 o;
    o.x = f2bf(v.x); o.y = f2bf(v.y); o.z = f2bf(v.z); o.w = f2bf(v.w);
    ((ushort4*)out)[i] = o;
  }
}

// ---------------- context projections + bias fold: E[64][3072] ----------------
__global__ __launch_bounds__(256) void k_ctx(
    const unsigned short* __restrict__ cjb, const unsigned short* __restrict__ heb,
    const unsigned short* __restrict__ Wchb, const unsigned short* __restrict__ Wzhb,
    const float* __restrict__ b_ih, const float* __restrict__ b_hh,
    const float* __restrict__ b_ch, const float* __restrict__ b_zh,
    float* __restrict__ E) {
  __shared__ f32x4 red[4][4][64];   // 16 KB
  int n0 = blockIdx.x * 16;         // 192 blocks
  int tid = threadIdx.x;
  int w = tid >> 6, l = tid & 63, lo = l & 15, hi = l >> 4;
  f32x4 acc[4];
#pragma unroll
  for (int r = 0; r < 4; r++) acc[r] = (f32x4){0.f, 0.f, 0.f, 0.f};
#pragma unroll 4
  for (int kk = 0; kk < 16; kk++) {
    int k = w * 512 + kk * 32;
    const unsigned short* Asrc = (k < 1024) ? cjb : heb;
    const unsigned short* Bsrc = (k < 1024) ? Wchb : Wzhb;
    int kw = (k < 1024) ? k : (k - 1024);
    int kof = kw + hi * 8;
    short8 bf = *(const short8*)(Bsrc + (size_t)(n0 + lo) * 1024 + kof);
#pragma unroll
    for (int r = 0; r < 4; r++) {
      short8 af = *(const short8*)(Asrc + (size_t)(r * 16 + lo) * 1024 + kof);
      acc[r] = mfma16(af, bf, acc[r]);
    }
  }
#pragma unroll
  for (int r = 0; r < 4; r++) red[w][r][l] = acc[r];
  __syncthreads();
  f32x4 s = red[0][w][l];
#pragma unroll
  for (int w2 = 1; w2 < 4; w2++) {
    f32x4 p = red[w2][w][l];
    s[0] += p[0]; s[1] += p[1]; s[2] += p[2]; s[3] += p[3];
  }
  int g = n0 + lo;
  float bias = b_ih[g] + b_ch[g] + b_zh[g] + ((g < 2048) ? b_hh[g] : 0.0f);
#pragma unroll
  for (int j = 0; j < 4; j++) {
    int b = w * 16 + hi * 4 + j;
    E[(size_t)b * G3 + g] = s[j] + bias;
  }
}

// ---------------- gi GEMM + E fold: giE[t*64+b][g] = X@Wih^T + E[b][g] (bf16) --------
__global__ __launch_bounds__(256) void k_gemm_gi(
    const unsigned short* __restrict__ Xb,   // [16384][1024] bf16
    const unsigned short* __restrict__ Wb,   // [3072][1024] bf16
    const float* __restrict__ E,             // [64][3072] f32
    unsigned short* __restrict__ gi) {       // [16384][3072] bf16
  __shared__ unsigned short As[128 * 32];
  __shared__ unsigned short Bs[128 * 32];
  int bid = blockIdx.x;
  int mt = bid & 127;
  int nt = bid >> 7;
  int m0 = mt * 128, n0 = nt * 128;
  int tid = threadIdx.x;
  int w = tid >> 6, l = tid & 63, lo = l & 15, hi = l >> 4;
  int wr = w >> 1, wc = w & 1;
  f32x4 acc[4][4];
#pragma unroll
  for (int i = 0; i < 4; i++)
#pragma unroll
    for (int j = 0; j < 4; j++) acc[i][j] = (f32x4){0.f, 0.f, 0.f, 0.f};
  int srow = tid >> 2;
  int scol = (tid & 3) * 8;
  for (int kt = 0; kt < 32; kt++) {
    int k0 = kt * 32;
    __syncthreads();
    gload_lds16(Xb + (size_t)(m0 + srow) * 1024 + k0 + scol, As + srow * 32 + scol);
    gload_lds16(Xb + (size_t)(m0 + 64 + srow) * 1024 + k0 + scol, As + (64 + srow) * 32 + scol);
    gload_lds16(Wb + (size_t)(n0 + srow) * 1024 + k0 + scol, Bs + srow * 32 + scol);
    gload_lds16(Wb + (size_t)(n0 + 64 + srow) * 1024 + k0 + scol, Bs + (64 + srow) * 32 + scol);
    asm volatile("s_waitcnt vmcnt(0)" ::: "memory");
    __syncthreads();
    short8 a[4], b[4];
#pragma unroll
    for (int i = 0; i < 4; i++) a[i] = *(const short8*)(As + (wr * 64 + i * 16 + lo) * 32 + hi * 8);
#pragma unroll
    for (int i = 0; i < 4; i++) b[i] = *(const short8*)(Bs + (wc * 64 + i * 16 + lo) * 32 + hi * 8);
#pragma unroll
    for (int i = 0; i < 4; i++)
#pragma unroll
      for (int j = 0; j < 4; j++) acc[i][j] = mfma16(a[i], b[j], acc[i][j]);
  }
#pragma unroll
  for (int i = 0; i < 4; i++)
#pragma unroll
    for (int j = 0; j < 4; j++)
#pragma unroll
      for (int e = 0; e < 4; e++) {
        int r = m0 + wr * 64 + i * 16 + hi * 4 + e;
        int c = n0 + wc * 64 + j * 16 + lo;
        float v = acc[i][j][e] + E[(size_t)(r & 63) * G3 + c];
        gi[(size_t)r * G3 + c] = f2bf(v);
      }
}

// ---------------- persistent recurrence kernel (v7) ----------------
// 64 wgs x 256 thr (4 waves). wg cs owns h cols [cs*16,+16). Wave kq owns
// K-slice [kq*256,+256) and computes ALL 4 row-tiles x 3 gates for it
// (B-frag loaded once from LDS, applied to 4 A-frags -> 4x less LDS B traffic
// than v6). After sync1, wave kq acts as updater for row-tile rt=kq.
// Weights pre-swizzled in LDS (96 KB). h exchange: transposed blocks
// hbuf[slot][colblock64][row64][16] bf16, TRIPLE buffered (slot = t mod 3).
// Sync: seq[cs][rt]; wave kq polls its 64 producer words (wgs kq*16..+16, all rt).
// sync1 (red ready) + sync2 (red reads done -> WAR-safe), then gates/publish/post.
__global__ __launch_bounds__(256) void k_rnn(
    const unsigned short* __restrict__ giE,   // [256*64][3072] bf16 (incl E)
    const unsigned short* __restrict__ Whhb,  // [3072][1024] bf16
    const float* __restrict__ b_hh,
    const float* __restrict__ h0,
    const int* __restrict__ length,
    unsigned short* __restrict__ hbuf,        // [3][64][64][16] bf16
    float* __restrict__ out,                  // [256][64][1024] f32
    float* __restrict__ hn,                   // [64][1024] f32
    unsigned int* __restrict__ seq) {         // [64 cs][4 rt] words, 64B-spaced
  extern __shared__ char smem[];
  unsigned short* wlds = (unsigned short*)smem;              // 96 KB [96 frag][64 lane][8]
  f32x4* red = (f32x4*)(smem + 98304);                       // 48 KB [4 kq][12][64]
  float* hp0 = (float*)(smem + 98304 + 49152);               // [2][16]

  const int cs = blockIdx.x;
  const int j0 = cs * 16;
  const int tid = threadIdx.x;
  const int kq = tid >> 6, l = tid & 63, lo = l & 15, hi = l >> 4;
  const int rowbase = kq * 16;          // epilogue row-tile = kq
  const int col = j0 + lo;

  // ---- weight preload: wave kq loads its 24 frags, fragment order ----
#pragma unroll
  for (int kk = 0; kk < 8; ++kk)
#pragma unroll
    for (int s = 0; s < 3; ++s) {
      int f = (kq * 8 + kk) * 3 + s;
      short8 v = *(const short8*)(Whhb + (size_t)(s * 1024 + j0 + lo) * 1024 + kq * 256 + kk * 32 + hi * 8);
      ((short8*)wlds)[f * 64 + l] = v;
    }

  const float bhhn = b_hh[2048 + col];
  float hown[4];
  int len4[4];
#pragma unroll
  for (int j = 0; j < 4; ++j) {
    int b = rowbase + hi * 4 + j;
    hown[j] = h0[(size_t)b * 1024 + col];
    len4[j] = length[b];
  }
  // publish h(0) into slot 0
#pragma unroll
  for (int j = 0; j < 4; ++j) {
    unsigned int mine = f2bf(hown[j]);
    unsigned int oth = __shfl_xor(mine, 1, 64);
    if (!(lo & 1)) {
      int row = rowbase + hi * 4 + j;
      __hip_atomic_store((unsigned int*)(hbuf + (size_t)cs * 1024 + row * 16 + lo),
                         mine | (oth << 16), __ATOMIC_RELAXED, __HIP_MEMORY_SCOPE_AGENT);
    }
  }
  if (kq == 0 && hi == 0) hp0[lo] = hown[0];
  float gir[3][4];
#pragma unroll
  for (int s = 0; s < 3; ++s)
#pragma unroll
    for (int j = 0; j < 4; ++j)
      gir[s][j] = bf2f(giE[(size_t)(rowbase + hi * 4 + j) * G3 + s * 1024 + col]);
  __syncthreads();   // wlds + hp0 ready
  asm volatile("s_waitcnt vmcnt(0)" ::: "memory");
  if (l == 0)
    __hip_atomic_store(&seq[(cs * 4 + kq) * 16], 1u, __ATOMIC_RELAXED, __HIP_MEMORY_SCOPE_AGENT);

  int slot = 0;
  for (int t = 0; t < TT; ++t) {
    const int nslot = (slot == 2) ? 0 : slot + 1;
    // ---- poll: lane l watches producer wg (kq*16 + l>>2), wave (l&3) ----
    {
      const unsigned int* sp = seq + ((size_t)(kq * 16 + (l >> 2)) * 4 + (l & 3)) * 16;
      unsigned int tgt = (unsigned int)(t + 1);
      for (;;) {
        unsigned int v = __hip_atomic_load(sp, __ATOMIC_RELAXED, __HIP_MEMORY_SCOPE_AGENT);
        if (__all(v >= tgt)) break;
        __builtin_amdgcn_s_sleep(1);
      }
    }
    // ---- GEMM: all 4 row-tiles x 3 strips for K-slice kq ----
    const unsigned short* hb2 = hbuf + (size_t)slot * 65536;
    union AF { ull u[2]; short8 v; };
    AF a[4][8];
#pragma unroll
    for (int rt = 0; rt < 4; ++rt)
#pragma unroll
      for (int kk = 0; kk < 8; ++kk) {
        int k = kq * 256 + kk * 32;
        int blk = (k >> 4) + (hi >> 1);
        const unsigned short* hp = hb2 + (size_t)blk * 1024 + (rt * 16 + lo) * 16 + (hi & 1) * 8;
        a[rt][kk].u[0] = __hip_atomic_load((const ull*)hp, __ATOMIC_RELAXED, __HIP_MEMORY_SCOPE_AGENT);
        a[rt][kk].u[1] = __hip_atomic_load((const ull*)hp + 1, __ATOMIC_RELAXED, __HIP_MEMORY_SCOPE_AGENT);
      }
    f32x4 acc[4][3];
#pragma unroll
    for (int rt = 0; rt < 4; ++rt)
#pragma unroll
      for (int s = 0; s < 3; ++s) acc[rt][s] = (f32x4){0.f, 0.f, 0.f, 0.f};
#pragma unroll
    for (int kk = 0; kk < 8; ++kk) {
      const short8* wf = ((const short8*)wlds) + (size_t)((kq * 8 + kk) * 3) * 64 + l;
      short8 b0 = wf[0];
      short8 b1 = wf[64];
      short8 b2 = wf[128];
#pragma unroll
      for (int rt = 0; rt < 4; ++rt) {
        acc[rt][0] = mfma16(a[rt][kk].v, b0, acc[rt][0]);
        acc[rt][1] = mfma16(a[rt][kk].v, b1, acc[rt][1]);
        acc[rt][2] = mfma16(a[rt][kk].v, b2, acc[rt][2]);
      }
    }
#pragma unroll
    for (int rt = 0; rt < 4; ++rt)
#pragma unroll
      for (int s = 0; s < 3; ++s)
        red[((size_t)kq * 12 + rt * 3 + s) * 64 + l] = acc[rt][s];
    __syncthreads();   // sync1: red ready
    // ---- reduce over kq for own row-tile rt=kq ----
    f32x4 fin[3];
#pragma unroll
    for (int s = 0; s < 3; ++s) {
      f32x4 v = red[((size_t)0 * 12 + kq * 3 + s) * 64 + l];
#pragma unroll
      for (int q = 1; q < 4; ++q) {
        f32x4 p = red[((size_t)q * 12 + kq * 3 + s) * 64 + l];
        v[0] += p[0]; v[1] += p[1]; v[2] += p[2]; v[3] += p[3];
      }
      fin[s] = v;
    }
    float h0p = hp0[(t & 1) * 16 + lo];
    __syncthreads();   // sync2: red reads done -> next-iter red writes WAR-safe
    // ---- gates + state update ----
    float hv[4];
#pragma unroll
    for (int j = 0; j < 4; ++j) {
      float R = fin[0][j] + gir[0][j];
      float I = fin[1][j] + gir[1][j];
      float rg = 1.f / (1.f + __expf(-R));
      float ig = 1.f / (1.f + __expf(-I));
      float nx = gir[2][j] + rg * (fin[2][j] + bhhn);
      nx = fminf(15.f, fmaxf(-15.f, nx));
      float e2 = __expf(2.f * nx);
      float ng = (e2 - 1.f) / (e2 + 1.f);
      float hy = ng + ig * (hown[j] - ng);
      float res = (t < len4[j]) ? hy : h0p;
      hv[j] = res;
      hown[j] = res;
    }
    if (t < TT - 1) {
      unsigned short* dst = hbuf + (size_t)nslot * 65536 + (size_t)cs * 1024;
#pragma unroll
      for (int j = 0; j < 4; ++j) {
        unsigned int mine = f2bf(hv[j]);
        unsigned int oth = __shfl_xor(mine, 1, 64);
        if (!(lo & 1)) {
          int row = rowbase + hi * 4 + j;
          __hip_atomic_store((unsigned int*)(dst + row * 16 + lo),
                             mine | (oth << 16), __ATOMIC_RELAXED, __HIP_MEMORY_SCOPE_AGENT);
        }
      }
      if (kq == 0 && hi == 0) hp0[((t + 1) & 1) * 16 + lo] = hv[0];
      asm volatile("s_waitcnt vmcnt(0)" ::: "memory");   // drain own h-stores
      if (l == 0)
        __hip_atomic_store(&seq[(cs * 4 + kq) * 16], (unsigned int)(t + 2),
                           __ATOMIC_RELAXED, __HIP_MEMORY_SCOPE_AGENT);
    }
    // ---- off-critical-path: out store + gi prefetch ----
#pragma unroll
    for (int j = 0; j < 4; ++j) {
      int b = rowbase + hi * 4 + j;
      out[(size_t)t * (BB * HH) + (size_t)b * 1024 + col] = hv[j];
    }
    if (t == TT - 1) {
#pragma unroll
      for (int j = 0; j < 4; ++j) {
        int b = rowbase + hi * 4 + j;
        hn[(size_t)b * 1024 + col] = hv[j];
      }
    } else {
      const unsigned short* gb = giE + (size_t)(t + 1) * 64 * G3;
#pragma unroll
      for (int s = 0; s < 3; ++s)
#pragma unroll
        for (int j = 0; j < 4; ++j)
          gir[s][j] = bf2f(gb[(size_t)(rowbase + hi * 4 + j) * G3 + s * 1024 + col]);
    }
    slot = nslot;
  }
}

// ---------------- host ----------------
extern "C" void kernel_launch(void* const* d_in, const int* in_sizes, int n_in,
                              void* d_out, int out_size, void* d_ws, size_t ws_size,
                              hipStream_t stream) {
  const float* input_ = (const float*)d_in[0];
  const int* length   = (const int*)d_in[1];
  const float* h0     = (const float*)d_in[2];
  const float* cj     = (const float*)d_in[3];
  const float* he     = (const float*)d_in[4];
  const float* w_ih   = (const float*)d_in[5];
  const float* w_hh   = (const float*)d_in[6];
  const float* w_ch   = (const float*)d_in[7];
  const float* w_zh   = (const float*)d_in[8];
  const float* b_ih   = (const float*)d_in[9];
  const float* b_hh   = (const float*)d_in[10];
  const float* b_ch   = (const float*)d_in[11];
  const float* b_zh   = (const float*)d_in[12];

  char* ws = (char*)d_ws;
  const size_t OFF_SEQ   = 0;              // 16 KB: [64][4] words, 64B-spaced
  const size_t OFF_XB    = 131072;
  const size_t OFF_WIHB  = OFF_XB + 33554432ull;
  const size_t OFF_WHHB  = OFF_WIHB + 6291456ull;
  const size_t OFF_WCHB  = OFF_WHHB + 6291456ull;
  const size_t OFF_WZHB  = OFF_WCHB + 6291456ull;
  const size_t OFF_CJB   = OFF_WZHB + 6291456ull;
  const size_t OFF_HEB   = OFF_CJB + 131072ull;
  const size_t OFF_E     = OFF_HEB + 131072ull;
  const size_t OFF_GI    = OFF_E + 786432ull;
  const size_t OFF_HBUF  = OFF_GI + 100663296ull;   // 3 x 131072 B

  unsigned int* seq     = (unsigned int*)(ws + OFF_SEQ);
  unsigned short* Xb    = (unsigned short*)(ws + OFF_XB);
  unsigned short* Wihb  = (unsigned short*)(ws + OFF_WIHB);
  unsigned short* Whhb  = (unsigned short*)(ws + OFF_WHHB);
  unsigned short* Wchb  = (unsigned short*)(ws + OFF_WCHB);
  unsigned short* Wzhb  = (unsigned short*)(ws + OFF_WZHB);
  unsigned short* cjb   = (unsigned short*)(ws + OFF_CJB);
  unsigned short* heb   = (unsigned short*)(ws + OFF_HEB);
  float* E              = (float*)(ws + OFF_E);
  unsigned short* gi    = (unsigned short*)(ws + OFF_GI);
  unsigned short* hbuf  = (unsigned short*)(ws + OFF_HBUF);

  float* out = (float*)d_out;
  float* hn  = out + 16777216;   // T*B*H

  hipFuncSetAttribute((const void*)k_rnn, hipFuncAttributeMaxDynamicSharedMemorySize, 147584);

  hipMemsetAsync(seq, 0, 16384, stream);
  k_cvt_bf16<<<2048, 256, 0, stream>>>(input_, Xb, 16777216 / 4);
  k_cvt_bf16<<<1024, 256, 0, stream>>>(w_ih, Wihb, 3145728 / 4);
  k_cvt_bf16<<<1024, 256, 0, stream>>>(w_hh, Whhb, 3145728 / 4);
  k_cvt_bf16<<<1024, 256, 0, stream>>>(w_ch, Wchb, 3145728 / 4);
  k_cvt_bf16<<<1024, 256, 0, stream>>>(w_zh, Wzhb, 3145728 / 4);
  k_cvt_bf16<<<64, 256, 0, stream>>>(cj, cjb, 65536 / 4);
  k_cvt_bf16<<<64, 256, 0, stream>>>(he, heb, 65536 / 4);
  k_ctx<<<192, 256, 0, stream>>>(cjb, heb, Wchb, Wzhb, b_ih, b_hh, b_ch, b_zh, E);
  k_gemm_gi<<<3072, 256, 0, stream>>>(Xb, Wihb, E, gi);
  k_rnn<<<64, 256, 147584, stream>>>(gi, Whhb, b_hh, h0, length, hbuf, out, hn, seq);
}

// Round 8
// 1444.041 us; speedup vs baseline: 2.7836x; 1.0071x over previous
//
#include <hip/hip_runtime.h>
#include <stdint.h>

#define TT 256
#define BB 64
#define DD 1024
#define HH 1024
#define G3 3072

typedef unsigned long long ull;
typedef __attribute__((ext_vector_type(8))) short short8;
typedef __attribute__((ext_vector_type(4))) float f32x4;

__device__ __forceinline__ unsigned short f2bf(float f) {
  union { float f; unsigned int i; } v; v.f = f;
  unsigned int x = v.i;
  return (unsigned short)((x + 0x7fffu + ((x >> 16) & 1u)) >> 16);
}
__device__ __forceinline__ float bf2f(unsigned short u) {
  union { unsigned int i; float f; } v; v.i = ((unsigned int)u) << 16; return v.f;
}
__device__ __forceinline__ f32x4 mfma16(short8 a, short8 b, f32x4 c) {
  return __builtin_amdgcn_mfma_f32_16x16x32_bf16(a, b, c, 0, 0, 0);
}
__device__ __forceinline__ void gload_lds16(const void* g, void* l) {
  __builtin_amdgcn_global_load_lds((const __attribute__((address_space(1))) void*)g,
                                   (__attribute__((address_space(3))) void*)l,
                                   16, 0, 0);
}
// 16B cache-bypass load (coherent read from MALL). Safe without atomicity:
// consumers only read after the seq protocol proves all producer stores landed.
__device__ __forceinline__ short8 mall_load16(const unsigned short* p) {
  short8 r;
  asm volatile("global_load_dwordx4 %0, %1, off sc0 sc1" : "=v"(r) : "v"(p));
  return r;
}

// ---------------- f32 -> bf16 convert (vectorized) ----------------
__global__ void k_cvt_bf16(const float* __restrict__ in, unsigned short* __restrict__ out, int n4) {
  int i = blockIdx.x * blockDim.x + threadIdx.x;
  int stride = gridDim.x * blockDim.x;
  for (; i < n4; i += stride) {
    float4 v = ((const float4*)in)[i];
    ushort4 o;
    o.x = f2bf(v.x); o.y = f2bf(v.y); o.z = f2bf(v.z); o.w = f2bf(v.w);
    ((ushort4*)out)[i] = o;
  }
}

// ---------------- context projections + bias fold: E[64][3072] ----------------
__global__ __launch_bounds__(256) void k_ctx(
    const unsigned short* __restrict__ cjb, const unsigned short* __restrict__ heb,
    const unsigned short* __restrict__ Wchb, const unsigned short* __restrict__ Wzhb,
    const float* __restrict__ b_ih, const float* __restrict__ b_hh,
    const float* __restrict__ b_ch, const float* __restrict__ b_zh,
    float* __restrict__ E) {
  __shared__ f32x4 red[4][4][64];   // 16 KB
  int n0 = blockIdx.x * 16;         // 192 blocks
  int tid = threadIdx.x;
  int w = tid >> 6, l = tid & 63, lo = l & 15, hi = l >> 4;
  f32x4 acc[4];
#pragma unroll
  for (int r = 0; r < 4; r++) acc[r] = (f32x4){0.f, 0.f, 0.f, 0.f};
#pragma unroll 4
  for (int kk = 0; kk < 16; kk++) {
    int k = w * 512 + kk * 32;
    const unsigned short* Asrc = (k < 1024) ? cjb : heb;
    const unsigned short* Bsrc = (k < 1024) ? Wchb : Wzhb;
    int kw = (k < 1024) ? k : (k - 1024);
    int kof = kw + hi * 8;
    short8 bf = *(const short8*)(Bsrc + (size_t)(n0 + lo) * 1024 + kof);
#pragma unroll
    for (int r = 0; r < 4; r++) {
      short8 af = *(const short8*)(Asrc + (size_t)(r * 16 + lo) * 1024 + kof);
      acc[r] = mfma16(af, bf, acc[r]);
    }
  }
#pragma unroll
  for (int r = 0; r < 4; r++) red[w][r][l] = acc[r];
  __syncthreads();
  f32x4 s = red[0][w][l];
#pragma unroll
  for (int w2 = 1; w2 < 4; w2++) {
    f32x4 p = red[w2][w][l];
    s[0] += p[0]; s[1] += p[1]; s[2] += p[2]; s[3] += p[3];
  }
  int g = n0 + lo;
  float bias = b_ih[g] + b_ch[g] + b_zh[g] + ((g < 2048) ? b_hh[g] : 0.0f);
#pragma unroll
  for (int j = 0; j < 4; j++) {
    int b = w * 16 + hi * 4 + j;
    E[(size_t)b * G3 + g] = s[j] + bias;
  }
}

// ---------------- gi GEMM + E fold: giE[t*64+b][g] = X@Wih^T + E[b][g] (bf16) --------
__global__ __launch_bounds__(256) void k_gemm_gi(
    const unsigned short* __restrict__ Xb,   // [16384][1024] bf16
    const unsigned short* __restrict__ Wb,   // [3072][1024] bf16
    const float* __restrict__ E,             // [64][3072] f32
    unsigned short* __restrict__ gi) {       // [16384][3072] bf16
  __shared__ unsigned short As[128 * 32];
  __shared__ unsigned short Bs[128 * 32];
  int bid = blockIdx.x;
  int mt = bid & 127;
  int nt = bid >> 7;
  int m0 = mt * 128, n0 = nt * 128;
  int tid = threadIdx.x;
  int w = tid >> 6, l = tid & 63, lo = l & 15, hi = l >> 4;
  int wr = w >> 1, wc = w & 1;
  f32x4 acc[4][4];
#pragma unroll
  for (int i = 0; i < 4; i++)
#pragma unroll
    for (int j = 0; j < 4; j++) acc[i][j] = (f32x4){0.f, 0.f, 0.f, 0.f};
  int srow = tid >> 2;
  int scol = (tid & 3) * 8;
  for (int kt = 0; kt < 32; kt++) {
    int k0 = kt * 32;
    __syncthreads();
    gload_lds16(Xb + (size_t)(m0 + srow) * 1024 + k0 + scol, As + srow * 32 + scol);
    gload_lds16(Xb + (size_t)(m0 + 64 + srow) * 1024 + k0 + scol, As + (64 + srow) * 32 + scol);
    gload_lds16(Wb + (size_t)(n0 + srow) * 1024 + k0 + scol, Bs + srow * 32 + scol);
    gload_lds16(Wb + (size_t)(n0 + 64 + srow) * 1024 + k0 + scol, Bs + (64 + srow) * 32 + scol);
    asm volatile("s_waitcnt vmcnt(0)" ::: "memory");
    __syncthreads();
    short8 a[4], b[4];
#pragma unroll
    for (int i = 0; i < 4; i++) a[i] = *(const short8*)(As + (wr * 64 + i * 16 + lo) * 32 + hi * 8);
#pragma unroll
    for (int i = 0; i < 4; i++) b[i] = *(const short8*)(Bs + (wc * 64 + i * 16 + lo) * 32 + hi * 8);
#pragma unroll
    for (int i = 0; i < 4; i++)
#pragma unroll
      for (int j = 0; j < 4; j++) acc[i][j] = mfma16(a[i], b[j], acc[i][j]);
  }
#pragma unroll
  for (int i = 0; i < 4; i++)
#pragma unroll
    for (int j = 0; j < 4; j++)
#pragma unroll
      for (int e = 0; e < 4; e++) {
        int r = m0 + wr * 64 + i * 16 + hi * 4 + e;
        int c = n0 + wc * 64 + j * 16 + lo;
        float v = acc[i][j][e] + E[(size_t)(r & 63) * G3 + c];
        gi[(size_t)r * G3 + c] = f2bf(v);
      }
}

// ---------------- persistent recurrence kernel (v8) ----------------
// 64 wgs x 512 thr (8 waves). Waves 0-3 = updaters (kq = K-slice, also row-tile
// rt=kq in epilogue) -- their ONLY vmem is: poll load, h loads (asm sc0sc1),
// h publish stores, seq store. Waves 4-7 = servants: prefetch gi(t+1)->LDS,
// write out(t-2) by reading back published bf16 h (2-barrier lag, race-free).
// Barrier windows per step: [work] sync1 [reduce/ds_write-gi] sync2 [gates/publish].
__global__ __launch_bounds__(512) void k_rnn(
    const unsigned short* __restrict__ giE,   // [256*64][3072] bf16 (incl E)
    const unsigned short* __restrict__ Whhb,  // [3072][1024] bf16
    const float* __restrict__ b_hh,
    const float* __restrict__ h0,
    const int* __restrict__ length,
    unsigned short* __restrict__ hbuf,        // [3][64][64][16] bf16
    float* __restrict__ out,                  // [256][64][1024] f32
    float* __restrict__ hn,                   // [64][1024] f32
    unsigned int* __restrict__ seq) {         // [64 cs][4 rt] words, 64B-spaced
  extern __shared__ char smem[];
  unsigned short* wlds = (unsigned short*)smem;            // 96 KB [96 frag][64 lane][8]
  f32x4* red = (f32x4*)(smem + 98304);                     // 48 KB [4 kq][12][64]
  unsigned short* giL = (unsigned short*)(smem + 147456);  // 13056 B [2][64][3*17 pad]
  float* hp0 = (float*)(smem + 160512);                    // [2][16]

  const int cs = blockIdx.x;
  const int j0 = cs * 16;
  const int tid = threadIdx.x;
  const int w = tid >> 6, l = tid & 63, lo = l & 15, hi = l >> 4;
  const bool is_upd = (w < 4);
  const int kq = w & 3;
  const int rowbase = kq * 16;
  const int col = j0 + lo;

  float bhhn = 0.f;
  float hown[4] = {0.f, 0.f, 0.f, 0.f};
  int len4[4] = {0, 0, 0, 0};

  if (is_upd) {
    // weight preload: wave kq loads its 24 frags in fragment order
#pragma unroll
    for (int kk = 0; kk < 8; ++kk)
#pragma unroll
      for (int s = 0; s < 3; ++s) {
        int f = (kq * 8 + kk) * 3 + s;
        short8 v = *(const short8*)(Whhb + (size_t)(s * 1024 + j0 + lo) * 1024 + kq * 256 + kk * 32 + hi * 8);
        ((short8*)wlds)[f * 64 + l] = v;
      }
    bhhn = b_hh[2048 + col];
#pragma unroll
    for (int j = 0; j < 4; ++j) {
      int b = rowbase + hi * 4 + j;
      hown[j] = h0[(size_t)b * 1024 + col];
      len4[j] = length[b];
    }
    // publish h(0) into slot 0
#pragma unroll
    for (int j = 0; j < 4; ++j) {
      unsigned int mine = f2bf(hown[j]);
      unsigned int oth = __shfl_xor(mine, 1, 64);
      if (!(lo & 1)) {
        int row = rowbase + hi * 4 + j;
        __hip_atomic_store((unsigned int*)(hbuf + (size_t)cs * 1024 + row * 16 + lo),
                           mine | (oth << 16), __ATOMIC_RELAXED, __HIP_MEMORY_SCOPE_AGENT);
      }
    }
    if (kq == 0 && hi == 0) hp0[lo] = hown[0];
  } else {
    // servant init: gi(0) -> giL parity 0
#pragma unroll
    for (int s = 0; s < 3; ++s)
#pragma unroll
      for (int j = 0; j < 4; ++j) {
        int b = rowbase + hi * 4 + j;
        giL[(size_t)(0 * 64 + b) * 51 + s * 17 + lo] =
            giE[(size_t)b * G3 + s * 1024 + col];
      }
  }
  __syncthreads();   // wlds + hp0 + giL[0] ready
  if (is_upd) {
    asm volatile("s_waitcnt vmcnt(0)" ::: "memory");   // drain h(0) stores
    if (l == 0)
      __hip_atomic_store(&seq[(cs * 4 + kq) * 16], 1u, __ATOMIC_RELAXED, __HIP_MEMORY_SCOPE_AGENT);
  }

  int slot = 0;
  for (int t = 0; t < TT; ++t) {
    const int nslot = (slot == 2) ? 0 : slot + 1;
    unsigned short gval[12];
    if (is_upd) {
      // ---- poll: lane l watches producer wg (kq*16 + l>>2), wave (l&3) ----
      const unsigned int* sp = seq + ((size_t)(kq * 16 + (l >> 2)) * 4 + (l & 3)) * 16;
      unsigned int tgt = (unsigned int)(t + 1);
      for (;;) {
        unsigned int v = __hip_atomic_load(sp, __ATOMIC_RELAXED, __HIP_MEMORY_SCOPE_AGENT);
        if (__all(v >= tgt)) break;
        __builtin_amdgcn_s_sleep(1);
      }
      // ---- h loads: 32 x 16B cache-bypass ----
      const unsigned short* hb2 = hbuf + (size_t)slot * 65536;
      short8 a[4][8];
#pragma unroll
      for (int rt = 0; rt < 4; ++rt)
#pragma unroll
        for (int kk = 0; kk < 8; ++kk) {
          int blk = kq * 16 + kk * 2 + (hi >> 1);
          a[rt][kk] = mall_load16(hb2 + (size_t)blk * 1024 + (rt * 16 + lo) * 16 + (hi & 1) * 8);
        }
      asm volatile("s_waitcnt vmcnt(0)" ::: "memory");
      __builtin_amdgcn_sched_barrier(0);
      // ---- GEMM: 4 row-tiles x 3 strips for K-slice kq ----
      f32x4 acc[4][3];
#pragma unroll
      for (int rt = 0; rt < 4; ++rt)
#pragma unroll
        for (int s = 0; s < 3; ++s) acc[rt][s] = (f32x4){0.f, 0.f, 0.f, 0.f};
#pragma unroll
      for (int kk = 0; kk < 8; ++kk) {
        const short8* wf = ((const short8*)wlds) + (size_t)((kq * 8 + kk) * 3) * 64 + l;
        short8 b0 = wf[0];
        short8 b1 = wf[64];
        short8 b2 = wf[128];
#pragma unroll
        for (int rt = 0; rt < 4; ++rt) {
          acc[rt][0] = mfma16(a[rt][kk], b0, acc[rt][0]);
          acc[rt][1] = mfma16(a[rt][kk], b1, acc[rt][1]);
          acc[rt][2] = mfma16(a[rt][kk], b2, acc[rt][2]);
        }
      }
#pragma unroll
      for (int rt = 0; rt < 4; ++rt)
#pragma unroll
        for (int s = 0; s < 3; ++s)
          red[((size_t)kq * 12 + rt * 3 + s) * 64 + l] = acc[rt][s];
    } else {
      // ---- servants: out(t-2) readback + gi(t+1) global loads ----
      if (t >= 2) {
        const unsigned short* hblk = hbuf + (size_t)((t + 2) % 3) * 65536 + (size_t)cs * 1024; // slot (t-1)%3 = h(t-1)
        int row = rowbase + (l >> 2);
        int c4 = (l & 3) * 4;
        ull d = __hip_atomic_load((const ull*)(hblk + row * 16 + c4),
                                  __ATOMIC_RELAXED, __HIP_MEMORY_SCOPE_AGENT);
        float4 o;
        o.x = bf2f((unsigned short)d);
        o.y = bf2f((unsigned short)(d >> 16));
        o.z = bf2f((unsigned short)(d >> 32));
        o.w = bf2f((unsigned short)(d >> 48));
        *(float4*)(out + (size_t)(t - 2) * (BB * HH) + (size_t)row * 1024 + j0 + c4) = o;
      }
      if (t < TT - 1) {
        const unsigned short* gb = giE + (size_t)(t + 1) * 64 * G3;
#pragma unroll
        for (int s = 0; s < 3; ++s)
#pragma unroll
          for (int j = 0; j < 4; ++j)
            gval[s * 4 + j] = gb[(size_t)(rowbase + hi * 4 + j) * G3 + s * 1024 + col];
      }
    }
    __syncthreads();   // sync1
    f32x4 fin[3];
    float h0p = 0.f;
    if (is_upd) {
      // ---- reduce over kq for own row-tile rt=kq ----
#pragma unroll
      for (int s = 0; s < 3; ++s) {
        f32x4 v = red[((size_t)0 * 12 + kq * 3 + s) * 64 + l];
#pragma unroll
        for (int q = 1; q < 4; ++q) {
          f32x4 p = red[((size_t)q * 12 + kq * 3 + s) * 64 + l];
          v[0] += p[0]; v[1] += p[1]; v[2] += p[2]; v[3] += p[3];
        }
        fin[s] = v;
      }
      h0p = hp0[(t & 1) * 16 + lo];
    } else if (t < TT - 1) {
      // servants commit gi(t+1) to LDS (ordered after all gir reads of parity t&1
      // because every updater's gir(t) read precedes its sync1(t) arrival... and
      // this write targets parity (t+1)&1, read at t+1 after sync2(t+1)).
#pragma unroll
      for (int s = 0; s < 3; ++s)
#pragma unroll
        for (int j = 0; j < 4; ++j) {
          int b = rowbase + hi * 4 + j;
          giL[(size_t)(((t + 1) & 1) * 64 + b) * 51 + s * 17 + lo] = gval[s * 4 + j];
        }
    }
    __syncthreads();   // sync2
    if (is_upd) {
      // ---- gates (gir from LDS) + publish + seq ----
      float gir_sj;
      float hv[4];
#pragma unroll
      for (int j = 0; j < 4; ++j) {
        int b = rowbase + hi * 4 + j;
        float g0 = bf2f(giL[(size_t)((t & 1) * 64 + b) * 51 + 0 * 17 + lo]);
        float g1 = bf2f(giL[(size_t)((t & 1) * 64 + b) * 51 + 1 * 17 + lo]);
        float g2 = bf2f(giL[(size_t)((t & 1) * 64 + b) * 51 + 2 * 17 + lo]);
        float R = fin[0][j] + g0;
        float I = fin[1][j] + g1;
        float rg = 1.f / (1.f + __expf(-R));
        float ig = 1.f / (1.f + __expf(-I));
        float nx = g2 + rg * (fin[2][j] + bhhn);
        nx = fminf(15.f, fmaxf(-15.f, nx));
        float e2 = __expf(2.f * nx);
        float ng = (e2 - 1.f) / (e2 + 1.f);
        float hy = ng + ig * (hown[j] - ng);
        float res = (t < len4[j]) ? hy : h0p;
        hv[j] = res;
        hown[j] = res;
      }
      (void)gir_sj;
      if (t < TT - 1) {
        unsigned short* dst = hbuf + (size_t)nslot * 65536 + (size_t)cs * 1024;
#pragma unroll
        for (int j = 0; j < 4; ++j) {
          unsigned int mine = f2bf(hv[j]);
          unsigned int oth = __shfl_xor(mine, 1, 64);
          if (!(lo & 1)) {
            int row = rowbase + hi * 4 + j;
            __hip_atomic_store((unsigned int*)(dst + row * 16 + lo),
                               mine | (oth << 16), __ATOMIC_RELAXED, __HIP_MEMORY_SCOPE_AGENT);
          }
        }
        if (kq == 0 && hi == 0) hp0[((t + 1) & 1) * 16 + lo] = hv[0];
        asm volatile("s_waitcnt vmcnt(0)" ::: "memory");   // drain own h-stores ONLY
        if (l == 0)
          __hip_atomic_store(&seq[(cs * 4 + kq) * 16], (unsigned int)(t + 2),
                             __ATOMIC_RELAXED, __HIP_MEMORY_SCOPE_AGENT);
      }
    }
    slot = nslot;
  }
  // ---- tail ----
  if (is_upd) {
    // out(TT-1) + hn from exact f32 registers
#pragma unroll
    for (int j = 0; j < 4; ++j) {
      int b = rowbase + hi * 4 + j;
      out[(size_t)(TT - 1) * (BB * HH) + (size_t)b * 1024 + col] = hown[j];
      hn[(size_t)b * 1024 + col] = hown[j];
    }
  } else {
    // out(TT-2) = h(TT-1), in slot (TT-1)%3 = 0
    const unsigned short* hblk = hbuf + (size_t)((TT - 1) % 3) * 65536 + (size_t)cs * 1024;
    int row = rowbase + (l >> 2);
    int c4 = (l & 3) * 4;
    ull d = __hip_atomic_load((const ull*)(hblk + row * 16 + c4),
                              __ATOMIC_RELAXED, __HIP_MEMORY_SCOPE_AGENT);
    float4 o;
    o.x = bf2f((unsigned short)d);
    o.y = bf2f((unsigned short)(d >> 16));
    o.z = bf2f((unsigned short)(d >> 32));
    o.w = bf2f((unsigned short)(d >> 48));
    *(float4*)(out + (size_t)(TT - 2) * (BB * HH) + (size_t)row * 1024 + j0 + c4) = o;
  }
}

// ---------------- host ----------------
extern "C" void kernel_launch(void* const* d_in, const int* in_sizes, int n_in,
                              void* d_out, int out_size, void* d_ws, size_t ws_size,
                              hipStream_t stream) {
  const float* input_ = (const float*)d_in[0];
  const int* length   = (const int*)d_in[1];
  const float* h0     = (const float*)d_in[2];
  const float* cj     = (const float*)d_in[3];
  const float* he     = (const float*)d_in[4];
  const float* w_ih   = (const float*)d_in[5];
  const float* w_hh   = (const float*)d_in[6];
  const float* w_ch   = (const float*)d_in[7];
  const float* w_zh   = (const float*)d_in[8];
  const float* b_ih   = (const float*)d_in[9];
  const float* b_hh   = (const float*)d_in[10];
  const float* b_ch   = (const float*)d_in[11];
  const float* b_zh   = (const float*)d_in[12];

  char* ws = (char*)d_ws;
  const size_t OFF_SEQ   = 0;              // 16 KB: [64][4] words, 64B-spaced
  const size_t OFF_XB    = 131072;
  const size_t OFF_WIHB  = OFF_XB + 33554432ull;
  const size_t OFF_WHHB  = OFF_WIHB + 6291456ull;
  const size_t OFF_WCHB  = OFF_WHHB + 6291456ull;
  const size_t OFF_WZHB  = OFF_WCHB + 6291456ull;
  const size_t OFF_CJB   = OFF_WZHB + 6291456ull;
  const size_t OFF_HEB   = OFF_CJB + 131072ull;
  const size_t OFF_E     = OFF_HEB + 131072ull;
  const size_t OFF_GI    = OFF_E + 786432ull;
  const size_t OFF_HBUF  = OFF_GI + 100663296ull;   // 3 x 131072 B

  unsigned int* seq     = (unsigned int*)(ws + OFF_SEQ);
  unsigned short* Xb    = (unsigned short*)(ws + OFF_XB);
  unsigned short* Wihb  = (unsigned short*)(ws + OFF_WIHB);
  unsigned short* Whhb  = (unsigned short*)(ws + OFF_WHHB);
  unsigned short* Wchb  = (unsigned short*)(ws + OFF_WCHB);
  unsigned short* Wzhb  = (unsigned short*)(ws + OFF_WZHB);
  unsigned short* cjb   = (unsigned short*)(ws + OFF_CJB);
  unsigned short* heb   = (unsigned short*)(ws + OFF_HEB);
  float* E              = (float*)(ws + OFF_E);
  unsigned short* gi    = (unsigned short*)(ws + OFF_GI);
  unsigned short* hbuf  = (unsigned short*)(ws + OFF_HBUF);

  float* out = (float*)d_out;
  float* hn  = out + 16777216;   // T*B*H

  hipFuncSetAttribute((const void*)k_rnn, hipFuncAttributeMaxDynamicSharedMemorySize, 160640);

  hipMemsetAsync(seq, 0, 16384, stream);
  k_cvt_bf16<<<2048, 256, 0, stream>>>(input_, Xb, 16777216 / 4);
  k_cvt_bf16<<<1024, 256, 0, stream>>>(w_ih, Wihb, 3145728 / 4);
  k_cvt_bf16<<<1024, 256, 0, stream>>>(w_hh, Whhb, 3145728 / 4);
  k_cvt_bf16<<<1024, 256, 0, stream>>>(w_ch, Wchb, 3145728 / 4);
  k_cvt_bf16<<<1024, 256, 0, stream>>>(w_zh, Wzhb, 3145728 / 4);
  k_cvt_bf16<<<64, 256, 0, stream>>>(cj, cjb, 65536 / 4);
  k_cvt_bf16<<<64, 256, 0, stream>>>(he, heb, 65536 / 4);
  k_ctx<<<192, 256, 0, stream>>>(cjb, heb, Wchb, Wzhb, b_ih, b_hh, b_ch, b_zh, E);
  k_gemm_gi<<<3072, 256, 0, stream>>>(Xb, Wihb, E, gi);
  k_rnn<<<64, 512, 160640, stream>>>(gi, Whhb, b_hh, h0, length, hbuf, out, hn, seq);
}